// Round 10
// baseline (261.548 us; speedup 1.0000x reference)
//
#include <hip/hip_runtime.h>
#include <hip/hip_bf16.h>
#include <math.h>

#define B_ 4
#define T_ 1024
#define C_ 1024
#define H_ 16
#define D_ 64
#define M_ (B_*T_)   /* 4096 rows */

typedef __bf16 bf16;
typedef __bf16 bf16x8 __attribute__((ext_vector_type(8)));
typedef float  f32x4  __attribute__((ext_vector_type(4)));

#define MFMA16(a, b, c) __builtin_amdgcn_mfma_f32_16x16x32_bf16((a), (b), (c), 0, 0, 0)

__device__ __forceinline__ void gload16(const void* g, void* l) {
  __builtin_amdgcn_global_load_lds((const __attribute__((address_space(1))) void*)g,
                                   (__attribute__((address_space(3))) void*)l,
                                   16, 0, 0);
}

// ============================================================================
// prep_k: ALL front-end work in one launch.
//   blocks [0, 3072):    64x64 weight transpose tiles (f32 -> bf16)
//     0-255 wq | 256-511 wk | 512-767 wv | 768-1023 wo | 1024-2047 w1 | 2048-3071 w2
//   blocks [3072, 7168): ln1 rows (4096)
//   blocks [7168, 7180): bias concat (3072 elems)
// ============================================================================
__global__ __launch_bounds__(256) void prep_k(
    const float* __restrict__ x, const float* __restrict__ ln1g,
    const float* __restrict__ ln1b,
    const float* __restrict__ wq, const float* __restrict__ wk,
    const float* __restrict__ wv, const float* __restrict__ wo,
    const float* __restrict__ w1, const float* __restrict__ w2,
    const float* __restrict__ bq, const float* __restrict__ bk,
    const float* __restrict__ bv,
    bf16* __restrict__ WqkvT, bf16* __restrict__ WoT,
    bf16* __restrict__ W1T, bf16* __restrict__ W2T,
    bf16* __restrict__ hbuf, float* __restrict__ bqkv) {
  __shared__ float tile[64][65];
  const int blk = blockIdx.x, tid = threadIdx.x;
  if (blk < 3072) {
    const float* W; bf16* WT; int K, N, n0, k0;
    if (blk < 1024)      { const int w = blk >> 8, t = blk & 255;
                           W  = (w == 0) ? wq : (w == 1) ? wk : (w == 2) ? wv : wo;
                           WT = (w < 3) ? WqkvT + (size_t)w * 1024 * 1024 : WoT;
                           K = 1024; N = 1024; n0 = (t & 15) * 64; k0 = (t >> 4) * 64; }
    else if (blk < 2048) { const int t = blk - 1024; W = w1; WT = W1T;
                           K = 1024; N = 4096; n0 = (t & 63) * 64; k0 = (t >> 6) * 64; }
    else                 { const int t = blk - 2048; W = w2; WT = W2T;
                           K = 4096; N = 1024; n0 = (t & 15) * 64; k0 = (t >> 4) * 64; }
    const int tr = tid >> 4, tc4 = (tid & 15) * 4;
#pragma unroll
    for (int p = 0; p < 4; ++p) {
      float4 v = *(const float4*)(W + (size_t)(k0 + tr + p * 16) * N + n0 + tc4);
      tile[tr + p * 16][tc4]     = v.x;
      tile[tr + p * 16][tc4 + 1] = v.y;
      tile[tr + p * 16][tc4 + 2] = v.z;
      tile[tr + p * 16][tc4 + 3] = v.w;
    }
    __syncthreads();
    const int nr = tid >> 3, k8 = (tid & 7) * 8;
#pragma unroll
    for (int p = 0; p < 2; ++p) {
      const int n = nr + p * 32;
      bf16x8 o8;
#pragma unroll
      for (int j = 0; j < 8; ++j) o8[j] = (bf16)tile[k8 + j][n];
      *(bf16x8*)(WT + (size_t)(n0 + n) * K + k0 + k8) = o8;
    }
  } else if (blk < 7168) {
    const int row = blk - 3072;
    float4 xv = ((const float4*)(x + (size_t)row * C_))[tid];
    float s  = xv.x + xv.y + xv.z + xv.w;
    float ss = xv.x*xv.x + xv.y*xv.y + xv.z*xv.z + xv.w*xv.w;
#pragma unroll
    for (int m = 32; m; m >>= 1) { s += __shfl_xor(s, m); ss += __shfl_xor(ss, m); }
    float* red = &tile[0][0];
    const int wid = tid >> 6;
    if ((tid & 63) == 0) { red[wid] = s; red[4 + wid] = ss; }
    __syncthreads();
    s  = red[0] + red[1] + red[2] + red[3];
    ss = red[4] + red[5] + red[6] + red[7];
    const float mean = s * (1.0f / C_);
    const float var  = ss * (1.0f / C_) - mean * mean;
    const float inv  = rsqrtf(var + 1e-5f);
    float4 gv = ((const float4*)ln1g)[tid];
    float4 bv = ((const float4*)ln1b)[tid];
    bf16* o = hbuf + (size_t)row * C_ + tid * 4;
    o[0] = (bf16)((xv.x - mean) * inv * gv.x + bv.x);
    o[1] = (bf16)((xv.y - mean) * inv * gv.y + bv.y);
    o[2] = (bf16)((xv.z - mean) * inv * gv.z + bv.z);
    o[3] = (bf16)((xv.w - mean) * inv * gv.w + bv.w);
  } else {
    const int i = (blk - 7168) * 256 + tid;  // 0..3071
    bqkv[i] = (i < 1024) ? bq[i] : ((i < 2048) ? bk[i - 1024] : bv[i - 2048]);
  }
}

// ---- LayerNorm (standalone, for ln2): x (rows x 1024) f32 -> out bf16
__global__ __launch_bounds__(256) void ln_k(const float* __restrict__ x,
                                            const float* __restrict__ g,
                                            const float* __restrict__ b,
                                            bf16* __restrict__ out) {
  int row = blockIdx.x;
  int t = threadIdx.x;
  float4 xv = ((const float4*)(x + (size_t)row * C_))[t];
  float s  = xv.x + xv.y + xv.z + xv.w;
  float ss = xv.x*xv.x + xv.y*xv.y + xv.z*xv.z + xv.w*xv.w;
#pragma unroll
  for (int m = 32; m; m >>= 1) { s += __shfl_xor(s, m); ss += __shfl_xor(ss, m); }
  __shared__ float red[8];
  int wid = t >> 6;
  if ((t & 63) == 0) { red[wid] = s; red[4 + wid] = ss; }
  __syncthreads();
  s  = red[0] + red[1] + red[2] + red[3];
  ss = red[4] + red[5] + red[6] + red[7];
  float mean = s * (1.0f / C_);
  float var  = ss * (1.0f / C_) - mean * mean;
  float inv  = rsqrtf(var + 1e-5f);
  float4 gv = ((const float4*)g)[t];
  float4 bv = ((const float4*)b)[t];
  bf16* o = out + (size_t)row * C_ + t * 4;
  o[0] = (bf16)((xv.x - mean) * inv * gv.x + bv.x);
  o[1] = (bf16)((xv.y - mean) * inv * gv.y + bv.y);
  o[2] = (bf16)((xv.z - mean) * inv * gv.z + bv.z);
  o[3] = (bf16)((xv.w - mean) * inv * gv.w + bv.w);
}

// ============================================================================
// m97-structure GEMM + stage-ahead (unchanged from R8/R9).
// ============================================================================
template <int BM, int BN, int WM, int WN, int EPI>
__global__ __launch_bounds__(WM*WN*64, 4)
void gemms(const bf16* __restrict__ A, const bf16* __restrict__ BT,
           const float* __restrict__ bias, const float* __restrict__ res,
           void* __restrict__ outp, int N, int K, int gx) {
  constexpr int NT = WM * WN * 64;          // 256
  constexpr int FM = BM / WM / 16, FN = BN / WN / 16;
  constexpr int RA = BM / 32, RB = BN / 32;
  __shared__ __align__(16) bf16 smem[(BM + BN) * 64];
  bf16* sA = smem;
  bf16* sB = smem + BM * 64;
  const int tid = threadIdx.x, lane = tid & 63, wid = tid >> 6;
  const int wr = wid / WN, wc = wid % WN;

  int bid = blockIdx.x;
  const int nwg = gridDim.x;
  if (!(nwg & 7)) bid = (bid & 7) * (nwg >> 3) + (bid >> 3);  // T1 (bijective)
  const int bx = bid % gx, by = bid / gx;
  const size_t am0 = (size_t)bx * BM, bn0 = (size_t)by * BN;

  f32x4 acc[FM][FN];
  const f32x4 fz = {0.f, 0.f, 0.f, 0.f};
#pragma unroll
  for (int m = 0; m < FM; ++m)
#pragma unroll
    for (int n = 0; n < FN; ++n) acc[m][n] = fz;

  const int srow = tid >> 3;
  const int sg = (tid & 7) ^ (srow & 7);
  const bf16* ag = A  + (am0 + srow) * (size_t)K + sg * 8;
  const bf16* bg = BT + (bn0 + srow) * (size_t)K + sg * 8;

  const int arow = lane & 15;
  const int g0 = (((lane >> 4))     ^ (lane & 7)) * 8;
  const int g1 = (((lane >> 4) + 4) ^ (lane & 7)) * 8;
  const int nt = K >> 6;

#pragma unroll
  for (int r = 0; r < RA; ++r)
    gload16(ag + (size_t)(r * 32) * K, sA + r * 2048 + tid * 8);
#pragma unroll
  for (int r = 0; r < RB; ++r)
    gload16(bg + (size_t)(r * 32) * K, sB + r * 2048 + tid * 8);

  for (int t = 0; t < nt; ++t) {
    __syncthreads();

    const bf16* pa = sA + (wr * (BM / WM) + arow) * 64;
    const bf16* pb = sB + (wc * (BN / WN) + arow) * 64;
    bf16x8 a[FM], b[FN];
#pragma unroll
    for (int m = 0; m < FM; ++m) a[m] = *(const bf16x8*)(pa + m * 16 * 64 + g0);
#pragma unroll
    for (int n = 0; n < FN; ++n) b[n] = *(const bf16x8*)(pb + n * 16 * 64 + g0);
#pragma unroll
    for (int m = 0; m < FM; ++m)
#pragma unroll
      for (int n = 0; n < FN; ++n)
        acc[m][n] = MFMA16(a[m], b[n], acc[m][n]);
    bf16x8 a1[FM], b1[FN];
#pragma unroll
    for (int m = 0; m < FM; ++m) a1[m] = *(const bf16x8*)(pa + m * 16 * 64 + g1);
#pragma unroll
    for (int n = 0; n < FN; ++n) b1[n] = *(const bf16x8*)(pb + n * 16 * 64 + g1);

    __syncthreads();

    if (t + 1 < nt) {
#pragma unroll
      for (int r = 0; r < RA; ++r)
        gload16(ag + (size_t)(t + 1) * 64 + (size_t)(r * 32) * K,
                sA + r * 2048 + tid * 8);
#pragma unroll
      for (int r = 0; r < RB; ++r)
        gload16(bg + (size_t)(t + 1) * 64 + (size_t)(r * 32) * K,
                sB + r * 2048 + tid * 8);
    }
#pragma unroll
    for (int m = 0; m < FM; ++m)
#pragma unroll
      for (int n = 0; n < FN; ++n)
        acc[m][n] = MFMA16(a1[m], b1[n], acc[m][n]);
  }

  if constexpr (EPI != 2) {
#pragma unroll
    for (int m = 0; m < FM; ++m) {
      const int row0 = wr * (BM / WM) + m * 16 + (lane >> 4) * 4;
#pragma unroll
      for (int n = 0; n < FN; ++n) {
        const int col = wc * (BN / WN) + n * 16 + (lane & 15);
        const float bv = bias[bn0 + col];
#pragma unroll
        for (int j = 0; j < 4; ++j) {
          float v = acc[m][n][j] + bv;
          if constexpr (EPI == 1) v = 0.5f * v * (1.0f + erff(v * 0.70710678118f));
          const int rr = row0 + j;
          smem[rr * BN + (((col >> 3) ^ (rr & 7)) << 3) + (col & 7)] = (bf16)v;
        }
      }
    }
    __syncthreads();
    constexpr int GR = BN / 8;
    constexpr int SI = BM * BN / (NT * 8);
#pragma unroll
    for (int i = 0; i < SI; ++i) {
      const int idx = i * NT + tid;
      const int row = idx / GR, g = idx % GR;
      *(bf16x8*)((bf16*)outp + (am0 + row) * N + bn0 + g * 8) =
          *(const bf16x8*)(smem + row * BN + ((g ^ (row & 7)) << 3));
    }
  } else {
    constexpr int PR = BM / WM;
    float* sf = (float*)smem;
#pragma unroll
    for (int h = 0; h < WM; ++h) {
      __syncthreads();
      if (wr == h) {
#pragma unroll
        for (int m = 0; m < FM; ++m) {
          const int lr0 = m * 16 + (lane >> 4) * 4;
#pragma unroll
          for (int n = 0; n < FN; ++n) {
            const int col = wc * (BN / WN) + n * 16 + (lane & 15);
            const float bv = bias[bn0 + col];
#pragma unroll
            for (int j = 0; j < 4; ++j)
              sf[(lr0 + j) * BN + col] = acc[m][n][j] + bv;
          }
        }
      }
      __syncthreads();
      constexpr int SI = PR * BN / (NT * 4);
#pragma unroll
      for (int i = 0; i < SI; ++i) {
        const int flat = (i * NT + tid) * 4;
        const int row = flat / BN, c = flat % BN;
        const size_t gi = (am0 + h * PR + row) * N + bn0 + c;
        float4 rv = *(const float4*)(res + gi);
        float4 sv = *(const float4*)(sf + row * BN + c);
        rv.x += sv.x; rv.y += sv.y; rv.z += sv.z; rv.w += sv.w;
        *(float4*)((float*)outp + gi) = rv;
      }
    }
  }
}

// ============================================================================
// flash attention (causal), R10: R9 pipeline (dbuf sK/sVT, 1 barrier/kt,
// XOR-swizzled, stage issued right after barrier) + TWO 64-row q-subtiles per
// block sharing each staged K/V tile: halves staging + barriers per FLOP,
// doubles compute cover per stage.  Block (bh, u) owns rows u*128..u*128+127.
// Fully-masked (s0, kt==2u+1) subtile skipped.
// ============================================================================
__global__ __launch_bounds__(256, 4) void attn_k(const bf16* __restrict__ Q,
                                                 const bf16* __restrict__ Kb,
                                                 const bf16* __restrict__ Vb,
                                                 bf16* __restrict__ Y, int ld) {
  const int bh = blockIdx.x;
  const int b = bh >> 4, h = bh & 15;
  const int u = (int)gridDim.y - 1 - (int)blockIdx.y;   // longest first
  const int q0 = u * 128;
  const int tid = threadIdx.x, wid = tid >> 6, lane = tid & 63;

  __shared__ __align__(16) bf16 sK[2][64 * 64];
  __shared__ __align__(16) bf16 sVT[2][64 * 64];
  __shared__ __align__(16) bf16 sP[4][16 * 64];

  const size_t rowQ0 = (size_t)(b * T_ + q0 + wid * 16 + (lane & 15)) * ld + h * 64 + (lane >> 4) * 8;
  const bf16x8 qaf0 = *(const bf16x8*)(Q + rowQ0);
  const bf16x8 qaf1 = *(const bf16x8*)(Q + rowQ0 + 32);
  const size_t rowQ1 = rowQ0 + (size_t)64 * ld;
  const bf16x8 qbf0 = *(const bf16x8*)(Q + rowQ1);
  const bf16x8 qbf1 = *(const bf16x8*)(Q + rowQ1 + 32);

  const f32x4 fz = {0.f, 0.f, 0.f, 0.f};
  float mA[4] = {-1e30f, -1e30f, -1e30f, -1e30f}, lA[4] = {0.f, 0.f, 0.f, 0.f};
  float mB[4] = {-1e30f, -1e30f, -1e30f, -1e30f}, lB[4] = {0.f, 0.f, 0.f, 0.f};
  f32x4 oA[4], oB[4];
#pragma unroll
  for (int i = 0; i < 4; ++i) { oA[i] = fz; oB[i] = fz; }

  const int kgr = (lane & 7) ^ (lane >> 3);
  const bf16* kg = Kb + (size_t)(b * T_ + wid * 16 + (lane >> 3)) * ld + h * 64 + kgr * 8;
  const int lkoff = (wid * 16) * 64;
  const bf16* vg = Vb + (size_t)(b * T_ + lane) * ld + h * 64;

  const int g0 = (((lane >> 4))     ^ (lane & 7)) * 8;
  const int g1 = (((lane >> 4) + 4) ^ (lane & 7)) * 8;

  // ---- prologue: stage kt=0 into buf 0
  gload16(kg,                   sK[0] + lkoff);
  gload16(kg + (size_t)8 * ld,  sK[0] + lkoff + 8 * 64);
  {
    bf16x8 v0 = *(const bf16x8*)(vg + wid * 8);
    bf16x8 v1 = *(const bf16x8*)(vg + (wid + 4) * 8);
#pragma unroll
    for (int j = 0; j < 8; ++j) {
      const int pc = ((((lane >> 3) ^ j) << 3) | (lane & 7));
      sVT[0][(wid * 8 + j) * 64 + pc]       = v0[j];
      sVT[0][((wid + 4) * 8 + j) * 64 + pc] = v1[j];
    }
  }

  const int ktmax = 2 * u + 1;
  int k0 = 0, cur = 0;

  // per-subtile compute (unrolled static indexing throughout)
  auto subtile = [&](const bf16x8& qf0, const bf16x8& qf1, int rbase,
                     float* m_run, float* l_run, f32x4* o) {
    f32x4 s[4];
#pragma unroll
    for (int ni = 0; ni < 4; ++ni) {
      const bf16* kr = sK[cur] + (ni * 16 + (lane & 15)) * 64;
      bf16x8 kf0 = *(const bf16x8*)(kr + g0);
      bf16x8 kf1 = *(const bf16x8*)(kr + g1);
      f32x4 t = fz;
      t = MFMA16(qf0, kf0, t);
      t = MFMA16(qf1, kf1, t);
      s[ni] = t;
    }
    const int cbase = k0 + (lane & 15);
    float tm[4] = {-1e30f, -1e30f, -1e30f, -1e30f};
#pragma unroll
    for (int ni = 0; ni < 4; ++ni)
#pragma unroll
      for (int j = 0; j < 4; ++j) {
        float v = s[ni][j] * 0.125f;
        if (cbase + ni * 16 > rbase + j) v = -1e30f;   // causal mask
        s[ni][j] = v;
        tm[j] = fmaxf(tm[j], v);
      }
#pragma unroll
    for (int j = 0; j < 4; ++j)
#pragma unroll
      for (int mk = 1; mk < 16; mk <<= 1)
        tm[j] = fmaxf(tm[j], __shfl_xor(tm[j], mk));

    float fac[4], rs[4] = {0.f, 0.f, 0.f, 0.f};
#pragma unroll
    for (int j = 0; j < 4; ++j) {
      float mn = fmaxf(m_run[j], tm[j]);
      fac[j] = __expf(m_run[j] - mn);
      m_run[j] = mn;
    }
#pragma unroll
    for (int ni = 0; ni < 4; ++ni)
#pragma unroll
      for (int j = 0; j < 4; ++j) {
        float p = __expf(s[ni][j] - m_run[j]);
        rs[j] += p;
        const int crow = (lane >> 4) * 4 + j;
        const int cg = (ni * 2 + ((lane & 15) >> 3)) ^ (crow & 7);
        sP[wid][crow * 64 + (cg << 3) + (lane & 7)] = (bf16)p;
      }
#pragma unroll
    for (int j = 0; j < 4; ++j) {
#pragma unroll
      for (int mk = 1; mk < 16; mk <<= 1)
        rs[j] += __shfl_xor(rs[j], mk);
      l_run[j] = l_run[j] * fac[j] + rs[j];
    }
#pragma unroll
    for (int df = 0; df < 4; ++df)
#pragma unroll
      for (int j = 0; j < 4; ++j)
        o[df][j] *= fac[j];
#pragma unroll
    for (int kk = 0; kk < 2; ++kk) {
      const int gk = kk ? g1 : g0;
      bf16x8 pf8 = *(const bf16x8*)(sP[wid] + (lane & 15) * 64 + gk);
#pragma unroll
      for (int df = 0; df < 4; ++df) {
        bf16x8 vf = *(const bf16x8*)(sVT[cur] + (df * 16 + (lane & 15)) * 64 + gk);
        o[df] = MFMA16(pf8, vf, o[df]);
      }
    }
  };

  for (int kt = 0; kt <= ktmax; ++kt) {
    cur = kt & 1;
    const int nxt = cur ^ 1;
    const bool pf = (kt < ktmax);
    __syncthreads();   // drains K gloads; V writes visible

    bf16x8 vn0, vn1;
    if (pf) {
      const size_t k1 = (size_t)(kt + 1) * 64;
      gload16(kg + k1 * ld,        sK[nxt] + lkoff);
      gload16(kg + (k1 + 8) * ld,  sK[nxt] + lkoff + 8 * 64);
      vn0 = *(const bf16x8*)(vg + k1 * ld + wid * 8);
      vn1 = *(const bf16x8*)(vg + k1 * ld + (wid + 4) * 8);
    }

    k0 = kt * 64;
    const int rb = q0 + wid * 16 + (lane >> 4) * 4;
    if (kt < ktmax)                 // s0 fully masked only at kt==ktmax
      subtile(qaf0, qaf1, rb,      mA, lA, oA);
    subtile(qbf0, qbf1, rb + 64,   mB, lB, oB);

    if (pf) {
#pragma unroll
      for (int j = 0; j < 8; ++j) {
        const int pc = ((((lane >> 3) ^ j) << 3) | (lane & 7));
        sVT[nxt][(wid * 8 + j) * 64 + pc]       = vn0[j];
        sVT[nxt][((wid + 4) * 8 + j) * 64 + pc] = vn1[j];
      }
    }
  }

#pragma unroll
  for (int df = 0; df < 4; ++df)
#pragma unroll
    for (int j = 0; j < 4; ++j) {
      const int row = q0 + wid * 16 + (lane >> 4) * 4 + j;
      const int d = df * 16 + (lane & 15);
      Y[(size_t)(b * T_ + row) * C_ + h * 64 + d]      = (bf16)(oA[df][j] / lA[j]);
      Y[(size_t)(b * T_ + row + 64) * C_ + h * 64 + d] = (bf16)(oB[df][j] / lB[j]);
    }
}

extern "C" void kernel_launch(void* const* d_in, const int* in_sizes, int n_in,
                              void* d_out, int out_size, void* d_ws, size_t ws_size,
                              hipStream_t stream) {
  (void)in_sizes; (void)n_in; (void)out_size; (void)ws_size;
  const float* x    = (const float*)d_in[0];
  const float* ln1g = (const float*)d_in[1];
  const float* ln1b = (const float*)d_in[2];
  const float* wq   = (const float*)d_in[3];
  const float* bq   = (const float*)d_in[4];
  const float* wk   = (const float*)d_in[5];
  const float* bk   = (const float*)d_in[6];
  const float* wv   = (const float*)d_in[7];
  const float* bv   = (const float*)d_in[8];
  const float* wo   = (const float*)d_in[9];
  const float* bo   = (const float*)d_in[10];
  const float* ln2g = (const float*)d_in[11];
  const float* ln2b = (const float*)d_in[12];
  const float* w1   = (const float*)d_in[13];
  const float* b1   = (const float*)d_in[14];
  const float* w2   = (const float*)d_in[15];
  const float* b2   = (const float*)d_in[16];

  char* ws = (char*)d_ws;
  const size_t MB = 1024 * 1024;
  bf16* WqkvT = (bf16*)(ws +  0 * MB);   // 6 MB  (3072 x 1024)
  bf16* WoT   = (bf16*)(ws +  6 * MB);   // 2 MB
  bf16* W1T   = (bf16*)(ws +  8 * MB);   // 8 MB
  bf16* W2T   = (bf16*)(ws + 16 * MB);   // 8 MB
  bf16* hbuf  = (bf16*)(ws + 24 * MB);   // 8 MB (ln1 out; reused for ln2 out)
  bf16* qkv   = (bf16*)(ws + 32 * MB);   // 24 MB (4096 x 3072)
  bf16* yb    = (bf16*)(ws + 56 * MB);   // 8 MB
  bf16* mb    = (bf16*)(ws + 32 * MB);   // 32 MB, reuses qkv+yb (dead by then)
  float* x1   = (float*)(ws + 64 * MB);  // 16 MB     -> total 80 MB
  float* bqkv = (float*)d_out;           // 12 KB scratch; d_out rewritten at end

  dim3 blk(256);
  prep_k<<<7180, blk, 0, stream>>>(x, ln1g, ln1b, wq, wk, wv, wo, w1, w2,
                                   bq, bk, bv, WqkvT, WoT, W1T, W2T, hbuf, bqkv);
  gemms<128,128,2,2,0><<<768,  blk, 0, stream>>>(hbuf, WqkvT, bqkv, nullptr, qkv, 3072, 1024, 32);
  attn_k<<<dim3(64, 8), blk, 0, stream>>>(qkv, qkv + 1024, qkv + 2048, yb, 3072);
  gemms<64,128,2,2,2><<<512,   blk, 0, stream>>>(yb, WoT, bo, x, x1, 1024, 1024, 64);
  ln_k<<<M_, blk, 0, stream>>>(x1, ln2g, ln2b, hbuf);
  gemms<128,128,2,2,1><<<1024, blk, 0, stream>>>(hbuf, W1T, b1, nullptr, mb, 4096, 1024, 32);
  gemms<64,128,2,2,2><<<512,   blk, 0, stream>>>(mb, W2T, b2, x1, (float*)d_out, 1024, 4096, 64);
}

// Round 11
// 210.713 us; speedup vs baseline: 1.2413x; 1.2413x over previous
//
#include <hip/hip_runtime.h>
#include <hip/hip_bf16.h>
#include <math.h>

#define B_ 4
#define T_ 1024
#define C_ 1024
#define H_ 16
#define D_ 64
#define M_ (B_*T_)   /* 4096 rows */

typedef __bf16 bf16;
typedef __bf16 bf16x8 __attribute__((ext_vector_type(8)));
typedef float  f32x4  __attribute__((ext_vector_type(4)));

#define MFMA16(a, b, c) __builtin_amdgcn_mfma_f32_16x16x32_bf16((a), (b), (c), 0, 0, 0)

__device__ __forceinline__ void gload16(const void* g, void* l) {
  __builtin_amdgcn_global_load_lds((const __attribute__((address_space(1))) void*)g,
                                   (__attribute__((address_space(3))) void*)l,
                                   16, 0, 0);
}

// ============================================================================
// prep_k: ALL front-end work in one launch (kept from R10 -- measured win).
//   blocks [0, 3072):    64x64 weight transpose tiles (f32 -> bf16)
//   blocks [3072, 7168): ln1 rows (4096)
//   blocks [7168, 7180): bias concat (3072 elems)
// ============================================================================
__global__ __launch_bounds__(256) void prep_k(
    const float* __restrict__ x, const float* __restrict__ ln1g,
    const float* __restrict__ ln1b,
    const float* __restrict__ wq, const float* __restrict__ wk,
    const float* __restrict__ wv, const float* __restrict__ wo,
    const float* __restrict__ w1, const float* __restrict__ w2,
    const float* __restrict__ bq, const float* __restrict__ bk,
    const float* __restrict__ bv,
    bf16* __restrict__ WqkvT, bf16* __restrict__ WoT,
    bf16* __restrict__ W1T, bf16* __restrict__ W2T,
    bf16* __restrict__ hbuf, float* __restrict__ bqkv) {
  __shared__ float tile[64][65];
  const int blk = blockIdx.x, tid = threadIdx.x;
  if (blk < 3072) {
    const float* W; bf16* WT; int K, N, n0, k0;
    if (blk < 1024)      { const int w = blk >> 8, t = blk & 255;
                           W  = (w == 0) ? wq : (w == 1) ? wk : (w == 2) ? wv : wo;
                           WT = (w < 3) ? WqkvT + (size_t)w * 1024 * 1024 : WoT;
                           K = 1024; N = 1024; n0 = (t & 15) * 64; k0 = (t >> 4) * 64; }
    else if (blk < 2048) { const int t = blk - 1024; W = w1; WT = W1T;
                           K = 1024; N = 4096; n0 = (t & 63) * 64; k0 = (t >> 6) * 64; }
    else                 { const int t = blk - 2048; W = w2; WT = W2T;
                           K = 4096; N = 1024; n0 = (t & 15) * 64; k0 = (t >> 4) * 64; }
    const int tr = tid >> 4, tc4 = (tid & 15) * 4;
#pragma unroll
    for (int p = 0; p < 4; ++p) {
      float4 v = *(const float4*)(W + (size_t)(k0 + tr + p * 16) * N + n0 + tc4);
      tile[tr + p * 16][tc4]     = v.x;
      tile[tr + p * 16][tc4 + 1] = v.y;
      tile[tr + p * 16][tc4 + 2] = v.z;
      tile[tr + p * 16][tc4 + 3] = v.w;
    }
    __syncthreads();
    const int nr = tid >> 3, k8 = (tid & 7) * 8;
#pragma unroll
    for (int p = 0; p < 2; ++p) {
      const int n = nr + p * 32;
      bf16x8 o8;
#pragma unroll
      for (int j = 0; j < 8; ++j) o8[j] = (bf16)tile[k8 + j][n];
      *(bf16x8*)(WT + (size_t)(n0 + n) * K + k0 + k8) = o8;
    }
  } else if (blk < 7168) {
    const int row = blk - 3072;
    float4 xv = ((const float4*)(x + (size_t)row * C_))[tid];
    float s  = xv.x + xv.y + xv.z + xv.w;
    float ss = xv.x*xv.x + xv.y*xv.y + xv.z*xv.z + xv.w*xv.w;
#pragma unroll
    for (int m = 32; m; m >>= 1) { s += __shfl_xor(s, m); ss += __shfl_xor(ss, m); }
    float* red = &tile[0][0];
    const int wid = tid >> 6;
    if ((tid & 63) == 0) { red[wid] = s; red[4 + wid] = ss; }
    __syncthreads();
    s  = red[0] + red[1] + red[2] + red[3];
    ss = red[4] + red[5] + red[6] + red[7];
    const float mean = s * (1.0f / C_);
    const float var  = ss * (1.0f / C_) - mean * mean;
    const float inv  = rsqrtf(var + 1e-5f);
    float4 gv = ((const float4*)ln1g)[tid];
    float4 bv = ((const float4*)ln1b)[tid];
    bf16* o = hbuf + (size_t)row * C_ + tid * 4;
    o[0] = (bf16)((xv.x - mean) * inv * gv.x + bv.x);
    o[1] = (bf16)((xv.y - mean) * inv * gv.y + bv.y);
    o[2] = (bf16)((xv.z - mean) * inv * gv.z + bv.z);
    o[3] = (bf16)((xv.w - mean) * inv * gv.w + bv.w);
  } else {
    const int i = (blk - 7168) * 256 + tid;  // 0..3071
    bqkv[i] = (i < 1024) ? bq[i] : ((i < 2048) ? bk[i - 1024] : bv[i - 2048]);
  }
}

// ---- LayerNorm (standalone, for ln2): x (rows x 1024) f32 -> out bf16
__global__ __launch_bounds__(256) void ln_k(const float* __restrict__ x,
                                            const float* __restrict__ g,
                                            const float* __restrict__ b,
                                            bf16* __restrict__ out) {
  int row = blockIdx.x;
  int t = threadIdx.x;
  float4 xv = ((const float4*)(x + (size_t)row * C_))[t];
  float s  = xv.x + xv.y + xv.z + xv.w;
  float ss = xv.x*xv.x + xv.y*xv.y + xv.z*xv.z + xv.w*xv.w;
#pragma unroll
  for (int m = 32; m; m >>= 1) { s += __shfl_xor(s, m); ss += __shfl_xor(ss, m); }
  __shared__ float red[8];
  int wid = t >> 6;
  if ((t & 63) == 0) { red[wid] = s; red[4 + wid] = ss; }
  __syncthreads();
  s  = red[0] + red[1] + red[2] + red[3];
  ss = red[4] + red[5] + red[6] + red[7];
  float mean = s * (1.0f / C_);
  float var  = ss * (1.0f / C_) - mean * mean;
  float inv  = rsqrtf(var + 1e-5f);
  float4 gv = ((const float4*)g)[t];
  float4 bv = ((const float4*)b)[t];
  bf16* o = out + (size_t)row * C_ + t * 4;
  o[0] = (bf16)((xv.x - mean) * inv * gv.x + bv.x);
  o[1] = (bf16)((xv.y - mean) * inv * gv.y + bv.y);
  o[2] = (bf16)((xv.z - mean) * inv * gv.z + bv.z);
  o[3] = (bf16)((xv.w - mean) * inv * gv.w + bv.w);
}

// ============================================================================
// m97-structure GEMM + stage-ahead (unchanged from R8/R9).
// ============================================================================
template <int BM, int BN, int WM, int WN, int EPI>
__global__ __launch_bounds__(WM*WN*64, 4)
void gemms(const bf16* __restrict__ A, const bf16* __restrict__ BT,
           const float* __restrict__ bias, const float* __restrict__ res,
           void* __restrict__ outp, int N, int K, int gx) {
  constexpr int NT = WM * WN * 64;          // 256
  constexpr int FM = BM / WM / 16, FN = BN / WN / 16;
  constexpr int RA = BM / 32, RB = BN / 32;
  __shared__ __align__(16) bf16 smem[(BM + BN) * 64];
  bf16* sA = smem;
  bf16* sB = smem + BM * 64;
  const int tid = threadIdx.x, lane = tid & 63, wid = tid >> 6;
  const int wr = wid / WN, wc = wid % WN;

  int bid = blockIdx.x;
  const int nwg = gridDim.x;
  if (!(nwg & 7)) bid = (bid & 7) * (nwg >> 3) + (bid >> 3);  // T1 (bijective)
  const int bx = bid % gx, by = bid / gx;
  const size_t am0 = (size_t)bx * BM, bn0 = (size_t)by * BN;

  f32x4 acc[FM][FN];
  const f32x4 fz = {0.f, 0.f, 0.f, 0.f};
#pragma unroll
  for (int m = 0; m < FM; ++m)
#pragma unroll
    for (int n = 0; n < FN; ++n) acc[m][n] = fz;

  const int srow = tid >> 3;
  const int sg = (tid & 7) ^ (srow & 7);
  const bf16* ag = A  + (am0 + srow) * (size_t)K + sg * 8;
  const bf16* bg = BT + (bn0 + srow) * (size_t)K + sg * 8;

  const int arow = lane & 15;
  const int g0 = (((lane >> 4))     ^ (lane & 7)) * 8;
  const int g1 = (((lane >> 4) + 4) ^ (lane & 7)) * 8;
  const int nt = K >> 6;

#pragma unroll
  for (int r = 0; r < RA; ++r)
    gload16(ag + (size_t)(r * 32) * K, sA + r * 2048 + tid * 8);
#pragma unroll
  for (int r = 0; r < RB; ++r)
    gload16(bg + (size_t)(r * 32) * K, sB + r * 2048 + tid * 8);

  for (int t = 0; t < nt; ++t) {
    __syncthreads();

    const bf16* pa = sA + (wr * (BM / WM) + arow) * 64;
    const bf16* pb = sB + (wc * (BN / WN) + arow) * 64;
    bf16x8 a[FM], b[FN];
#pragma unroll
    for (int m = 0; m < FM; ++m) a[m] = *(const bf16x8*)(pa + m * 16 * 64 + g0);
#pragma unroll
    for (int n = 0; n < FN; ++n) b[n] = *(const bf16x8*)(pb + n * 16 * 64 + g0);
#pragma unroll
    for (int m = 0; m < FM; ++m)
#pragma unroll
      for (int n = 0; n < FN; ++n)
        acc[m][n] = MFMA16(a[m], b[n], acc[m][n]);
    bf16x8 a1[FM], b1[FN];
#pragma unroll
    for (int m = 0; m < FM; ++m) a1[m] = *(const bf16x8*)(pa + m * 16 * 64 + g1);
#pragma unroll
    for (int n = 0; n < FN; ++n) b1[n] = *(const bf16x8*)(pb + n * 16 * 64 + g1);

    __syncthreads();

    if (t + 1 < nt) {
#pragma unroll
      for (int r = 0; r < RA; ++r)
        gload16(ag + (size_t)(t + 1) * 64 + (size_t)(r * 32) * K,
                sA + r * 2048 + tid * 8);
#pragma unroll
      for (int r = 0; r < RB; ++r)
        gload16(bg + (size_t)(t + 1) * 64 + (size_t)(r * 32) * K,
                sB + r * 2048 + tid * 8);
    }
#pragma unroll
    for (int m = 0; m < FM; ++m)
#pragma unroll
      for (int n = 0; n < FN; ++n)
        acc[m][n] = MFMA16(a1[m], b1[n], acc[m][n]);
  }

  if constexpr (EPI != 2) {
#pragma unroll
    for (int m = 0; m < FM; ++m) {
      const int row0 = wr * (BM / WM) + m * 16 + (lane >> 4) * 4;
#pragma unroll
      for (int n = 0; n < FN; ++n) {
        const int col = wc * (BN / WN) + n * 16 + (lane & 15);
        const float bv = bias[bn0 + col];
#pragma unroll
        for (int j = 0; j < 4; ++j) {
          float v = acc[m][n][j] + bv;
          if constexpr (EPI == 1) v = 0.5f * v * (1.0f + erff(v * 0.70710678118f));
          const int rr = row0 + j;
          smem[rr * BN + (((col >> 3) ^ (rr & 7)) << 3) + (col & 7)] = (bf16)v;
        }
      }
    }
    __syncthreads();
    constexpr int GR = BN / 8;
    constexpr int SI = BM * BN / (NT * 8);
#pragma unroll
    for (int i = 0; i < SI; ++i) {
      const int idx = i * NT + tid;
      const int row = idx / GR, g = idx % GR;
      *(bf16x8*)((bf16*)outp + (am0 + row) * N + bn0 + g * 8) =
          *(const bf16x8*)(smem + row * BN + ((g ^ (row & 7)) << 3));
    }
  } else {
    constexpr int PR = BM / WM;
    float* sf = (float*)smem;
#pragma unroll
    for (int h = 0; h < WM; ++h) {
      __syncthreads();
      if (wr == h) {
#pragma unroll
        for (int m = 0; m < FM; ++m) {
          const int lr0 = m * 16 + (lane >> 4) * 4;
#pragma unroll
          for (int n = 0; n < FN; ++n) {
            const int col = wc * (BN / WN) + n * 16 + (lane & 15);
            const float bv = bias[bn0 + col];
#pragma unroll
            for (int j = 0; j < 4; ++j)
              sf[(lr0 + j) * BN + col] = acc[m][n][j] + bv;
          }
        }
      }
      __syncthreads();
      constexpr int SI = PR * BN / (NT * 4);
#pragma unroll
      for (int i = 0; i < SI; ++i) {
        const int flat = (i * NT + tid) * 4;
        const int row = flat / BN, c = flat % BN;
        const size_t gi = (am0 + h * PR + row) * N + bn0 + c;
        float4 rv = *(const float4*)(res + gi);
        float4 sv = *(const float4*)(sf + row * BN + c);
        rv.x += sv.x; rv.y += sv.y; rv.z += sv.z; rv.w += sv.w;
        *(float4*)((float*)outp + gi) = rv;
      }
    }
  }
}

// ============================================================================
// flash attention (causal) -- EXACT R9 version (measured ~24 us): dbuf
// sK/sVT, ONE barrier per K/V-tile, XOR swizzle, 1024-block grid (4/CU).
// R10's 2-subtile variant reverted (grid 512 -> 2 blocks/CU killed overlap).
// ============================================================================
__global__ __launch_bounds__(256) void attn_k(const bf16* __restrict__ Q,
                                              const bf16* __restrict__ Kb,
                                              const bf16* __restrict__ Vb,
                                              bf16* __restrict__ Y, int ld) {
  int bh = blockIdx.x;
  int b = bh >> 4, h = bh & 15;
  int qt = (int)gridDim.y - 1 - (int)blockIdx.y;   // longest first
  int q0 = qt * 64;
  int tid = threadIdx.x, wid = tid >> 6, lane = tid & 63;

  __shared__ __align__(16) bf16 sK[2][64 * 64];
  __shared__ __align__(16) bf16 sVT[2][64 * 64];
  __shared__ __align__(16) bf16 sP[4][16 * 64];

  const size_t rowQ = (size_t)(b * T_ + q0 + wid * 16 + (lane & 15)) * ld + h * 64 + (lane >> 4) * 8;
  bf16x8 qf0 = *(const bf16x8*)(Q + rowQ);
  bf16x8 qf1 = *(const bf16x8*)(Q + rowQ + 32);

  float m_run[4] = {-1e30f, -1e30f, -1e30f, -1e30f};
  float l_run[4] = {0.f, 0.f, 0.f, 0.f};
  const f32x4 fz = {0.f, 0.f, 0.f, 0.f};
  f32x4 o[4];
#pragma unroll
  for (int i = 0; i < 4; ++i) o[i] = fz;

  const int kgr = (lane & 7) ^ (lane >> 3);
  const bf16* kg = Kb + (size_t)(b * T_ + wid * 16 + (lane >> 3)) * ld + h * 64 + kgr * 8;
  const int lkoff = (wid * 16) * 64;
  const bf16* vg = Vb + (size_t)(b * T_ + lane) * ld + h * 64;

  const int g0 = (((lane >> 4))     ^ (lane & 7)) * 8;
  const int g1 = (((lane >> 4) + 4) ^ (lane & 7)) * 8;

  // ---- prologue: stage kt=0 into buf 0
  gload16(kg,                   sK[0] + lkoff);
  gload16(kg + (size_t)8 * ld,  sK[0] + lkoff + 8 * 64);
  {
    bf16x8 v0 = *(const bf16x8*)(vg + wid * 8);
    bf16x8 v1 = *(const bf16x8*)(vg + (wid + 4) * 8);
#pragma unroll
    for (int j = 0; j < 8; ++j) {
      const int pc = ((((lane >> 3) ^ j) << 3) | (lane & 7));
      sVT[0][(wid * 8 + j) * 64 + pc]       = v0[j];
      sVT[0][((wid + 4) * 8 + j) * 64 + pc] = v1[j];
    }
  }

  for (int kt = 0; kt <= qt; ++kt) {
    const int cur = kt & 1, nxt = cur ^ 1;
    const bool pf = (kt < qt);
    __syncthreads();   // drains K gloads; V writes visible

    bf16x8 vn0, vn1;
    if (pf) {          // issue next tile's staging NOW
      const size_t k1 = (size_t)(kt + 1) * 64;
      gload16(kg + k1 * ld,        sK[nxt] + lkoff);
      gload16(kg + (k1 + 8) * ld,  sK[nxt] + lkoff + 8 * 64);
      vn0 = *(const bf16x8*)(vg + k1 * ld + wid * 8);
      vn1 = *(const bf16x8*)(vg + k1 * ld + (wid + 4) * 8);
    }

    const int k0 = kt * 64;
    f32x4 s[4];
#pragma unroll
    for (int ni = 0; ni < 4; ++ni) {
      const bf16* kr = sK[cur] + (ni * 16 + (lane & 15)) * 64;
      bf16x8 kf0 = *(const bf16x8*)(kr + g0);
      bf16x8 kf1 = *(const bf16x8*)(kr + g1);
      f32x4 t = fz;
      t = MFMA16(qf0, kf0, t);
      t = MFMA16(qf1, kf1, t);
      s[ni] = t;
    }

    int rbase = q0 + wid * 16 + (lane >> 4) * 4;
    int cbase = k0 + (lane & 15);
    float tm[4] = {-1e30f, -1e30f, -1e30f, -1e30f};
#pragma unroll
    for (int ni = 0; ni < 4; ++ni)
#pragma unroll
      for (int j = 0; j < 4; ++j) {
        float v = s[ni][j] * 0.125f;
        if (cbase + ni * 16 > rbase + j) v = -1e30f;   // causal mask
        s[ni][j] = v;
        tm[j] = fmaxf(tm[j], v);
      }
#pragma unroll
    for (int j = 0; j < 4; ++j)
#pragma unroll
      for (int mk = 1; mk < 16; mk <<= 1)
        tm[j] = fmaxf(tm[j], __shfl_xor(tm[j], mk));

    float fac[4], rs[4] = {0.f, 0.f, 0.f, 0.f};
#pragma unroll
    for (int j = 0; j < 4; ++j) {
      float mn = fmaxf(m_run[j], tm[j]);
      fac[j] = __expf(m_run[j] - mn);
      m_run[j] = mn;
    }
#pragma unroll
    for (int ni = 0; ni < 4; ++ni)
#pragma unroll
      for (int j = 0; j < 4; ++j) {
        float p = __expf(s[ni][j] - m_run[j]);
        rs[j] += p;
        const int crow = (lane >> 4) * 4 + j;
        const int cg = (ni * 2 + ((lane & 15) >> 3)) ^ (crow & 7);
        sP[wid][crow * 64 + (cg << 3) + (lane & 7)] = (bf16)p;
      }
#pragma unroll
    for (int j = 0; j < 4; ++j) {
#pragma unroll
      for (int mk = 1; mk < 16; mk <<= 1)
        rs[j] += __shfl_xor(rs[j], mk);
      l_run[j] = l_run[j] * fac[j] + rs[j];
    }
#pragma unroll
    for (int df = 0; df < 4; ++df)
#pragma unroll
      for (int j = 0; j < 4; ++j)
        o[df][j] *= fac[j];

#pragma unroll
    for (int kk = 0; kk < 2; ++kk) {
      const int gk = kk ? g1 : g0;
      bf16x8 pf8 = *(const bf16x8*)(sP[wid] + (lane & 15) * 64 + gk);
#pragma unroll
      for (int df = 0; df < 4; ++df) {
        bf16x8 vf = *(const bf16x8*)(sVT[cur] + (df * 16 + (lane & 15)) * 64 + gk);
        o[df] = MFMA16(pf8, vf, o[df]);
      }
    }

    if (pf) {          // write next V tile into nxt buf (vmcnt wait lands here)
#pragma unroll
      for (int j = 0; j < 8; ++j) {
        const int pc = ((((lane >> 3) ^ j) << 3) | (lane & 7));
        sVT[nxt][(wid * 8 + j) * 64 + pc]       = vn0[j];
        sVT[nxt][((wid + 4) * 8 + j) * 64 + pc] = vn1[j];
      }
    }
  }

#pragma unroll
  for (int df = 0; df < 4; ++df)
#pragma unroll
    for (int j = 0; j < 4; ++j) {
      int row = q0 + wid * 16 + (lane >> 4) * 4 + j;
      int d = df * 16 + (lane & 15);
      Y[(size_t)(b * T_ + row) * C_ + h * 64 + d] = (bf16)(o[df][j] / l_run[j]);
    }
}

extern "C" void kernel_launch(void* const* d_in, const int* in_sizes, int n_in,
                              void* d_out, int out_size, void* d_ws, size_t ws_size,
                              hipStream_t stream) {
  (void)in_sizes; (void)n_in; (void)out_size; (void)ws_size;
  const float* x    = (const float*)d_in[0];
  const float* ln1g = (const float*)d_in[1];
  const float* ln1b = (const float*)d_in[2];
  const float* wq   = (const float*)d_in[3];
  const float* bq   = (const float*)d_in[4];
  const float* wk   = (const float*)d_in[5];
  const float* bk   = (const float*)d_in[6];
  const float* wv   = (const float*)d_in[7];
  const float* bv   = (const float*)d_in[8];
  const float* wo   = (const float*)d_in[9];
  const float* bo   = (const float*)d_in[10];
  const float* ln2g = (const float*)d_in[11];
  const float* ln2b = (const float*)d_in[12];
  const float* w1   = (const float*)d_in[13];
  const float* b1   = (const float*)d_in[14];
  const float* w2   = (const float*)d_in[15];
  const float* b2   = (const float*)d_in[16];

  char* ws = (char*)d_ws;
  const size_t MB = 1024 * 1024;
  bf16* WqkvT = (bf16*)(ws +  0 * MB);   // 6 MB  (3072 x 1024)
  bf16* WoT   = (bf16*)(ws +  6 * MB);   // 2 MB
  bf16* W1T   = (bf16*)(ws +  8 * MB);   // 8 MB
  bf16* W2T   = (bf16*)(ws + 16 * MB);   // 8 MB
  bf16* hbuf  = (bf16*)(ws + 24 * MB);   // 8 MB (ln1 out; reused for ln2 out)
  bf16* qkv   = (bf16*)(ws + 32 * MB);   // 24 MB (4096 x 3072)
  bf16* yb    = (bf16*)(ws + 56 * MB);   // 8 MB
  bf16* mb    = (bf16*)(ws + 32 * MB);   // 32 MB, reuses qkv+yb (dead by then)
  float* x1   = (float*)(ws + 64 * MB);  // 16 MB     -> total 80 MB
  float* bqkv = (float*)d_out;           // 12 KB scratch; d_out rewritten at end

  dim3 blk(256);
  prep_k<<<7180, blk, 0, stream>>>(x, ln1g, ln1b, wq, wk, wv, wo, w1, w2,
                                   bq, bk, bv, WqkvT, WoT, W1T, W2T, hbuf, bqkv);
  gemms<128,128,2,2,0><<<768,  blk, 0, stream>>>(hbuf, WqkvT, bqkv, nullptr, qkv, 3072, 1024, 32);
  attn_k<<<dim3(64, 16), blk, 0, stream>>>(qkv, qkv + 1024, qkv + 2048, yb, 3072);
  gemms<64,128,2,2,2><<<512,   blk, 0, stream>>>(yb, WoT, bo, x, x1, 1024, 1024, 64);
  ln_k<<<M_, blk, 0, stream>>>(x1, ln2g, ln2b, hbuf);
  gemms<128,128,2,2,1><<<1024, blk, 0, stream>>>(hbuf, W1T, b1, nullptr, mb, 4096, 1024, 32);
  gemms<64,128,2,2,2><<<512,   blk, 0, stream>>>(mb, W2T, b2, x1, (float*)d_out, 1024, 4096, 64);
}